// Round 7
// baseline (367.280 us; speedup 1.0000x reference)
//
#include <hip/hip_runtime.h>
#include <hip/hip_bf16.h>
#include <math.h>

typedef __bf16 bf16;
typedef __bf16 bf16x2 __attribute__((ext_vector_type(2)));
typedef __bf16 bf16x8 __attribute__((ext_vector_type(8)));
typedef float f32x4 __attribute__((ext_vector_type(4)));
typedef float f32x16 __attribute__((ext_vector_type(16)));
typedef unsigned int u32;
typedef unsigned int u32x2 __attribute__((ext_vector_type(2)));
typedef unsigned int u32x4 __attribute__((ext_vector_type(4)));

#define SCALE 0.125f

// async global->LDS, 16B per lane. LDS dest must be wave-uniform base + lane*16.
#define GLOAD_LDS16(gptr, lptr)                                      \
  __builtin_amdgcn_global_load_lds(                                  \
      (const __attribute__((address_space(1))) void*)(gptr),         \
      (__attribute__((address_space(3))) void*)(lptr), 16, 0, 0)

template <int N>
__device__ __forceinline__ void vmcnt_wait() {
  if constexpr (N == 0) asm volatile("s_waitcnt vmcnt(0)" ::: "memory");
  else if constexpr (N == 4) asm volatile("s_waitcnt vmcnt(4)" ::: "memory");
  else if constexpr (N == 6) asm volatile("s_waitcnt vmcnt(6)" ::: "memory");
  else static_assert(N == 0 || N == 4 || N == 6, "unsupported vmcnt");
}

// XCD-chunked bijective block swizzle (T1). Bijective for gx%8==0, nwg%8==0.
__device__ __forceinline__ void xcd_swz(int gx, int gy, int& x, int& y) {
  int w = blockIdx.x + gx * blockIdx.y;
  int nwg = gx * gy;
  int wp = (w & 7) * (nwg >> 3) + (w >> 3);
  int xi = wp & 7;
  int t = wp >> 3;
  y = t % gy;
  x = (t / gy) * 8 + xi;
}

// pack two f32 -> one u32 of 2 bf16 (RNE)
__device__ __forceinline__ u32 pk_bf16(float lo, float hi) {
  bf16x2 t;
  t[0] = (bf16)lo;
  t[1] = (bf16)hi;
  return __builtin_bit_cast(u32, t);
}

// v_permlane32_swap_b32: a.hi <-> b.lo
__device__ __forceinline__ void plane32_swap(u32& a, u32& b) {
  asm volatile("v_permlane32_swap_b32 %0, %1" : "+v"(a), "+v"(b));
}

// ---------------- row LayerNorm: fp32 in -> bf16 out ----------------
__global__ __launch_bounds__(256) void ln_f32(const float* __restrict__ x,
                                              const float* __restrict__ g,
                                              const float* __restrict__ b,
                                              bf16* __restrict__ y) {
  long base = (long)blockIdx.x * 1024;
  int tid = threadIdx.x;
  float v[4];
#pragma unroll
  for (int i = 0; i < 4; i++) v[i] = x[base + tid + i * 256];
  float s1 = v[0] + v[1] + v[2] + v[3];
  float s2 = v[0] * v[0] + v[1] * v[1] + v[2] * v[2] + v[3] * v[3];
#pragma unroll
  for (int off = 32; off; off >>= 1) {
    s1 += __shfl_xor(s1, off);
    s2 += __shfl_xor(s2, off);
  }
  __shared__ float aux[2][4];
  int wave = tid >> 6, lane = tid & 63;
  if (lane == 0) { aux[0][wave] = s1; aux[1][wave] = s2; }
  __syncthreads();
  float S1 = aux[0][0] + aux[0][1] + aux[0][2] + aux[0][3];
  float S2 = aux[1][0] + aux[1][1] + aux[1][2] + aux[1][3];
  float mean = S1 * (1.0f / 1024.0f);
  float var = S2 * (1.0f / 1024.0f) - mean * mean;
  float rs = rsqrtf(var + 1e-5f);
#pragma unroll
  for (int i = 0; i < 4; i++) {
    int c = tid + i * 256;
    y[base + c] = (bf16)(((v[i] - mean) * rs) * g[c] + b[c]);
  }
}

// ---------------- W[K][N] fp32 -> Wt[N][K] bf16 tiled transpose ----------------
__global__ __launch_bounds__(256) void transpose_w(const float* __restrict__ W,
                                                   bf16* __restrict__ Wt,
                                                   int K, int N) {
  __shared__ bf16 tile[64][66];
  int n0 = blockIdx.x * 64, k0 = blockIdx.y * 64;
  int c = threadIdx.x & 63, r4 = threadIdx.x >> 6;
#pragma unroll
  for (int i = 0; i < 16; i++)
    tile[i * 4 + r4][c] = (bf16)W[(long)(k0 + i * 4 + r4) * N + n0 + c];
  __syncthreads();
#pragma unroll
  for (int i = 0; i < 16; i++)
    Wt[(long)(n0 + i * 4 + r4) * K + k0 + c] = tile[c][i * 4 + r4];
}

// ------- extract V^T per (b,h) -------
__global__ __launch_bounds__(256) void extract_vt(const bf16* __restrict__ KV,
                                                  bf16* __restrict__ Vt) {
  __shared__ bf16 tile[64][66];
  int bh = blockIdx.z, b = bh >> 4, h = bh & 15;
  const bf16* src = KV + (long)b * 1024 * 2048 + 1024 + h * 64;
  bf16* dst = Vt + (long)bh * 64 * 1024;
  int n0 = blockIdx.x * 64;
  int c = threadIdx.x & 63, r4 = threadIdx.x >> 6;
#pragma unroll
  for (int i = 0; i < 16; i++)
    tile[i * 4 + r4][c] = src[(long)(n0 + i * 4 + r4) * 2048 + c];
  __syncthreads();
#pragma unroll
  for (int i = 0; i < 16; i++)
    dst[(long)(i * 4 + r4) * 1024 + n0 + c] = tile[c][i * 4 + r4];
}

// ---------------- fused flash attention, swapped-QK^T in-register softmax ----------------
__global__ __launch_bounds__(256) void attn_fused(
    const bf16* __restrict__ Q,   // [4096][1024]
    const bf16* __restrict__ KV,  // [4096][2048], K at col h*64
    const bf16* __restrict__ Vt,  // [64 bh][64 d][1024 n]
    bf16* __restrict__ X) {       // [4096][1024]
  __shared__ __align__(16) bf16 Qs[128 * 64];
  __shared__ __align__(16) bf16 Ks[2][64 * 128];
  __shared__ __align__(16) bf16 Vs[2][64 * 128];
  int tid = threadIdx.x, wave = tid >> 6, lane = tid & 63;
  int l31 = lane & 31, h = lane >> 5;
  int bqx, bhy;
  xcd_swz(8, 64, bqx, bhy);
  int bh = bhy, b = bh >> 4, hd = bh & 15;
  const bf16* Qb = Q + (long)b * 1048576 + hd * 64;
  const bf16* Kb = KV + (long)b * 2097152 + hd * 64;
  const bf16* Vb = Vt + (long)bh * 65536;
  bf16* Xb = X + (long)b * 1048576 + hd * 64;
  int q0 = bqx * 128;

  const bf16* gk[4];
  const bf16* gv[4];
  int eoKV[4];
#pragma unroll
  for (int t = 0; t < 4; t++) {
    int eo = (t * 256 + tid) * 8;
    eoKV[t] = eo;
    int r2 = eo >> 7, pp = (eo & 127) >> 3, q = pp ^ (r2 & 15);
    gk[t] = &Kb[(long)(r2 + ((q >> 3) << 6)) * 2048 + ((q & 7) << 3)];
    gv[t] = &Vb[(long)r2 * 1024 + (q << 3)];
  }

#pragma unroll
  for (int t = 0; t < 4; t++) {
    int eo = (t * 256 + tid) * 8;
    int r = eo >> 6, p = (eo & 63) >> 3;
    int c = (p ^ (r & 7)) << 3;
    GLOAD_LDS16(&Qb[(long)(q0 + r) * 1024 + c], &Qs[eo]);
  }
#pragma unroll
  for (int t = 0; t < 4; t++) GLOAD_LDS16(gk[t], &Ks[0][eoKV[t]]);
#pragma unroll
  for (int t = 0; t < 4; t++) GLOAD_LDS16(gv[t], &Vs[0][eoKV[t]]);
  __syncthreads();

  bf16x8 qf[4];
  {
    int r = wave * 32 + l31;
#pragma unroll
    for (int dw = 0; dw < 4; dw++) {
      int p = (dw * 2 + h) ^ (r & 7);
      qf[dw] = *(const bf16x8*)&Qs[r * 64 + p * 8];
    }
  }

  const float C = 0.18033688011112042f;  // SCALE * log2(e)
  float m_run = -1e30f, l_run = 0.0f;
  f32x16 acc[2] = {};
  int cur = 0;

  for (int kc = 0; kc < 8; kc++) {
    if (kc < 7) {
#pragma unroll
      for (int t = 0; t < 4; t++)
        GLOAD_LDS16(gk[t] + (long)(kc + 1) * 128 * 2048, &Ks[cur ^ 1][eoKV[t]]);
#pragma unroll
      for (int t = 0; t < 4; t++)
        GLOAD_LDS16(gv[t] + (kc + 1) * 128, &Vs[cur ^ 1][eoKV[t]]);
    }
    const bf16* ks = Ks[cur];
    const bf16* vs = Vs[cur];

    f32x16 s[4] = {};
#pragma unroll
    for (int kt = 0; kt < 4; kt++) {
      int k = kt * 32 + l31;
      int r2 = k & 63, hi = k >> 6;
#pragma unroll
      for (int dw = 0; dw < 4; dw++) {
        int p = (hi * 8 + dw * 2 + h) ^ (r2 & 15);
        bf16x8 kf = *(const bf16x8*)&ks[r2 * 128 + p * 8];
        s[kt] = __builtin_amdgcn_mfma_f32_32x32x16_bf16(kf, qf[dw], s[kt], 0, 0, 0);
      }
    }

    float mk[4];
#pragma unroll
    for (int kt = 0; kt < 4; kt++) {
      float m01 = fmaxf(fmaxf(s[kt][0], s[kt][1]), fmaxf(s[kt][2], s[kt][3]));
      float m23 = fmaxf(fmaxf(s[kt][4], s[kt][5]), fmaxf(s[kt][6], s[kt][7]));
      float m45 = fmaxf(fmaxf(s[kt][8], s[kt][9]), fmaxf(s[kt][10], s[kt][11]));
      float m67 = fmaxf(fmaxf(s[kt][12], s[kt][13]), fmaxf(s[kt][14], s[kt][15]));
      mk[kt] = fmaxf(fmaxf(m01, m23), fmaxf(m45, m67));
    }
    float mx = fmaxf(fmaxf(mk[0], mk[1]), fmaxf(mk[2], mk[3]));
    mx = fmaxf(mx, __shfl_xor(mx, 32));
    float m_new = fmaxf(m_run, mx);
    float alpha = exp2f((m_run - m_new) * C);
    m_run = m_new;
    float mc = m_new * C;
    float rk[4];
#pragma unroll
    for (int kt = 0; kt < 4; kt++) {
      float r0 = 0.0f;
#pragma unroll
      for (int r = 0; r < 16; r++) {
        float pv = exp2f(s[kt][r] * C - mc);
        s[kt][r] = pv;
        r0 += pv;
      }
      rk[kt] = r0;
    }
    float rs = (rk[0] + rk[1]) + (rk[2] + rk[3]);
    rs += __shfl_xor(rs, 32);
    l_run = l_run * alpha + rs;
#pragma unroll
    for (int nt = 0; nt < 2; nt++)
#pragma unroll
      for (int r = 0; r < 16; r++) acc[nt][r] *= alpha;

#pragma unroll
    for (int kw = 0; kw < 8; kw++) {
      int kt = kw >> 1, rb = (kw & 1) * 8;
      u32 wA = pk_bf16(s[kt][rb + 0], s[kt][rb + 1]);
      u32 wB = pk_bf16(s[kt][rb + 2], s[kt][rb + 3]);
      u32 wC = pk_bf16(s[kt][rb + 4], s[kt][rb + 5]);
      u32 wD = pk_bf16(s[kt][rb + 6], s[kt][rb + 7]);
      plane32_swap(wA, wC);
      plane32_swap(wB, wD);
      u32x4 wv = {wA, wB, wC, wD};
      bf16x8 pf = __builtin_bit_cast(bf16x8, wv);
#pragma unroll
      for (int nt = 0; nt < 2; nt++) {
        int r2 = nt * 32 + l31;
        int p = (kw * 2 + h) ^ (r2 & 15);
        bf16x8 vf = *(const bf16x8*)&vs[r2 * 128 + p * 8];
        acc[nt] = __builtin_amdgcn_mfma_f32_32x32x16_bf16(vf, pf, acc[nt], 0, 0, 0);
      }
    }

    if (kc < 7) {
      __syncthreads();
      cur ^= 1;
    }
  }

  float fs = SCALE / l_run;
  bf16* Os = Qs;
  int qrow = wave * 32 + l31;
#pragma unroll
  for (int nt = 0; nt < 2; nt++)
#pragma unroll
    for (int g = 0; g < 4; g++) {
      u32 w0 = pk_bf16(acc[nt][g * 4 + 0] * fs, acc[nt][g * 4 + 1] * fs);
      u32 w1 = pk_bf16(acc[nt][g * 4 + 2] * fs, acc[nt][g * 4 + 3] * fs);
      int s8 = nt * 8 + g * 2 + h;
      int phys = s8 ^ (qrow & 15);
      u32x2 wv = {w0, w1};
      *(u32x2*)&Os[qrow * 64 + phys * 4] = wv;
    }
  int rrow = wave * 32 + (lane >> 1);
  int cbase = (lane & 1) * 32;
#pragma unroll
  for (int t2 = 0; t2 < 4; t2++) {
    int s0 = (lane & 1) * 8 + t2 * 2;
    u32x2 a = *(u32x2*)&Os[rrow * 64 + ((s0 ^ (rrow & 15)) * 4)];
    u32x2 bb = *(u32x2*)&Os[rrow * 64 + (((s0 + 1) ^ (rrow & 15)) * 4)];
    u32x4 o4 = {a[0], a[1], bb[0], bb[1]};
    *(u32x4*)&Xb[(long)(q0 + rrow) * 1024 + cbase + t2 * 8] = o4;
  }
}

// ---------------- pipelined gemm_p (R4-best: pinned body), triple-buffered ----------------
template <int BM, int BN, int WR, int WC, int EPI, int CF32, int RBF16>
__global__ __launch_bounds__(512) void gemm_p(
    const bf16* __restrict__ A, int lda,
    const bf16* __restrict__ B, int ldb,
    void* __restrict__ Cv, int ldc, int K,
    const float* __restrict__ bias,
    const void* __restrict__ resv, int ldr) {
  constexpr int MT = BM / (16 * WR);
  constexpr int NT = BN / (16 * WC);
  constexpr int L = (BM + BN) / 64;
  constexpr int LA = BM / 64;
  constexpr int AE = BM * 64;
  constexpr int BUFE = (BM + BN) * 64;
  __shared__ __align__(16) bf16 lds[3 * BUFE];
  int tid = threadIdx.x;
  int wave = tid >> 6, lane = tid & 63;
  int wm = wave / WC, wn = wave % WC;
  int quad = lane >> 4, l16 = lane & 15;
  int bx, by;
  xcd_swz(gridDim.x, gridDim.y, bx, by);
  int m0 = by * BM, n0 = bx * BN;

  const bf16* gp[L];
  int lo[L];
#pragma unroll
  for (int i = 0; i < L; i++) {
    if (i < LA) {
      int eo = (i * 512 + tid) * 8;
      int r = eo >> 6, p = (eo & 63) >> 3;
      int c = (p ^ (r & 7)) << 3;
      gp[i] = &A[(long)(m0 + r) * lda + c];
      lo[i] = eo;
    } else {
      int eo = ((i - LA) * 512 + tid) * 8;
      int r = eo >> 6, p = (eo & 63) >> 3;
      int c = (p ^ (r & 7)) << 3;
      gp[i] = &B[(long)(n0 + r) * ldb + c];
      lo[i] = AE + eo;
    }
  }

  int ntk = K >> 6;
#pragma unroll
  for (int i = 0; i < L; i++) GLOAD_LDS16(gp[i], &lds[lo[i]]);
#pragma unroll
  for (int i = 0; i < L; i++) gp[i] += 64;
#pragma unroll
  for (int i = 0; i < L; i++) GLOAD_LDS16(gp[i], &lds[BUFE + lo[i]]);
#pragma unroll
  for (int i = 0; i < L; i++) gp[i] += 64;
  vmcnt_wait<L>();
  asm volatile("" ::: "memory");
  __builtin_amdgcn_s_barrier();

  f32x4 acc[MT][NT] = {};
  int b = 0;
  for (int t = 0; t < ntk; t++) {
    const bf16* Al = &lds[b * BUFE];
    const bf16* Bl = &lds[b * BUFE + AE];
    int b2 = b + 2; if (b2 >= 3) b2 -= 3;
    bool more = (t + 2) < ntk;

    bf16x8 af[2][MT], bv[2][NT];
#pragma unroll
    for (int ks = 0; ks < 2; ks++) {
#pragma unroll
      for (int mt = 0; mt < MT; mt++) {
        int row = wm * (BM / WR) + mt * 16 + l16;
        int p = (ks * 4 + quad) ^ (row & 7);
        af[ks][mt] = *(const bf16x8*)&Al[row * 64 + p * 8];
      }
#pragma unroll
      for (int nt = 0; nt < NT; nt++) {
        int row = wn * (BN / WC) + nt * 16 + l16;
        int p = (ks * 4 + quad) ^ (row & 7);
        bv[ks][nt] = *(const bf16x8*)&Bl[row * 64 + p * 8];
      }
    }
    if (more) {
#pragma unroll
      for (int i = 0; i < L; i++) GLOAD_LDS16(gp[i], &lds[b2 * BUFE + lo[i]]);
    }
    asm volatile("s_waitcnt lgkmcnt(0)" ::: "memory");
    __builtin_amdgcn_sched_barrier(0);
    __builtin_amdgcn_s_setprio(1);
#pragma unroll
    for (int ks = 0; ks < 2; ks++)
#pragma unroll
      for (int mt = 0; mt < MT; mt++)
#pragma unroll
        for (int nt = 0; nt < NT; nt++)
          acc[mt][nt] = __builtin_amdgcn_mfma_f32_16x16x32_bf16(
              af[ks][mt], bv[ks][nt], acc[mt][nt], 0, 0, 0);
    __builtin_amdgcn_s_setprio(0);
    __builtin_amdgcn_sched_barrier(0);
    if (more) {
      vmcnt_wait<L>();
    } else if (t + 1 < ntk) {
      vmcnt_wait<0>();
    }
    if (t + 1 < ntk) {
      asm volatile("" ::: "memory");
      __builtin_amdgcn_s_barrier();
    }
#pragma unroll
    for (int i = 0; i < L; i++) gp[i] += 64;
    b += 1; if (b == 3) b = 0;
  }

  int gm = m0 + wm * (BM / WR), gn = n0 + wn * (BN / WC);
#pragma unroll
  for (int nt = 0; nt < NT; nt++) {
    int col = gn + nt * 16 + l16;
    float bvb = (EPI != 0) ? bias[col] : 0.0f;
#pragma unroll
    for (int mt = 0; mt < MT; mt++) {
#pragma unroll
      for (int r = 0; r < 4; r++) {
        int row = gm + mt * 16 + quad * 4 + r;
        float v = acc[mt][nt][r] + bvb;
        if (EPI == 2) {
          v = 0.5f * v * (1.0f + erff(v * 0.70710678118654752f));
        } else if (EPI == 1) {
          float rv = RBF16 ? (float)((const bf16*)resv)[(long)row * ldr + col]
                           : ((const float*)resv)[(long)row * ldr + col];
          v += rv;
        }
        if (CF32)
          ((float*)Cv)[(long)row * ldc + col] = v;
        else
          ((bf16*)Cv)[(long)row * ldc + col] = (bf16)v;
      }
    }
  }
}

// ---------------- 8-phase 256x256 GEMM (m201 template; W1) ----------------
// 512 thr = 8 waves (2M x 4N), per-wave C = 128x64. BK=64 as 2 K-slices of 32.
// LDS per dbuf: A_k[2][256][32] + B_k[2][256][32]; 2 dbuf = 128 KB. Staging unit
// = one K-slice half (16 KB = 2 gloads/thread). Chunk swizzle: phys 16B-chunk
// p at row r holds logical chunk p^((r>>1)&3) -> 2-way on frag reads (free).
// Per K-tile t (dbuf t&1), 4 phases, each:
//   {ds_reads; stage 1 half; barrier; lgkmcnt(0); setprio(1); 16 MFMA; setprio(0); barrier}
//   ph0: read A_k0(8)+B_k0 ni01(2); stage B_k1(t+1)   [B_k1(t-1) last read ph3 of t-1]
//   ph1: read B_k0 ni23(2)+A_k1(8); stage A_k0(t+2)   [A_k0(t) last read ph0]
//   ph2: read B_k1 ni01(2);         stage A_k1(t+2)   [A_k1(t) last read ph1]
//   ph3: read B_k1 ni23(2);         stage B_k0(t+2);  [B_k0(t) last read ph1]
//        vmcnt(6)  <- newest 3 halves (ph1-3 stages) may remain; everything
//        older (incl. ALL of tile t+1) retired before t+1's reads. Never 0.
// Stage-write safety: a stage issued in phase p+1 follows phase-p's 2nd barrier,
// which every wave reaches only after its lgkmcnt(0) (reads retired).
template <int EPI, int CF32, int RBF16>
__global__ __launch_bounds__(512, 2) void gemm_8p(
    const bf16* __restrict__ A, int lda,
    const bf16* __restrict__ B, int ldb,
    void* __restrict__ Cv, int ldc, int K,
    const float* __restrict__ bias,
    const void* __restrict__ resv, int ldr) {
  __shared__ __align__(16) bf16 lds[65536];  // 128 KB
  int tid = threadIdx.x;
  int wave = tid >> 6, lane = tid & 63;
  int wm = wave >> 2, wn = wave & 3;
  int quad = lane >> 4, l16 = lane & 15;
  int bx, by;
  xcd_swz(gridDim.x, gridDim.y, bx, by);
  int m0 = by * 256, n0 = bx * 256;

  // staging sources (dest linear eo; src col inverse-swizzled within 32-col slice)
  int eo0 = tid * 8, eo1 = 4096 + tid * 8;
  const bf16 *sA0, *sA1, *sB0, *sB1;
  {
    int r0 = eo0 >> 5, p0 = (eo0 >> 3) & 3, q0 = p0 ^ ((r0 >> 1) & 3);
    int r1 = eo1 >> 5, p1 = (eo1 >> 3) & 3, q1 = p1 ^ ((r1 >> 1) & 3);
    sA0 = &A[(long)(m0 + r0) * lda + q0 * 8];
    sA1 = &A[(long)(m0 + r1) * lda + q1 * 8];
    sB0 = &B[(long)(n0 + r0) * ldb + q0 * 8];
    sB1 = &B[(long)(n0 + r1) * ldb + q1 * 8];
  }
  int ntk = K >> 6;

  // stage half j of K-tile ts: j0=A ks0, j1=A ks1, j2=B ks0, j3=B ks1
#define STAGE_HALF(ts, j)                                                     \
  {                                                                           \
    long ko = (long)(ts) * 64 + ((j) & 1) * 32;                               \
    int bas = (((ts) & 1) << 15) + (((j) >> 1) << 14) + (((j) & 1) << 13);    \
    if ((j) >> 1) {                                                           \
      GLOAD_LDS16(sB0 + ko, &lds[bas + eo0]);                                 \
      GLOAD_LDS16(sB1 + ko, &lds[bas + eo1]);                                 \
    } else {                                                                  \
      GLOAD_LDS16(sA0 + ko, &lds[bas + eo0]);                                 \
      GLOAD_LDS16(sA1 + ko, &lds[bas + eo1]);                                 \
    }                                                                         \
  }

  // prologue: tile0 fully + tile1 halves 0..2 (B_k1(1) comes from t=0 ph0)
  STAGE_HALF(0, 0) STAGE_HALF(0, 1) STAGE_HALF(0, 2) STAGE_HALF(0, 3)
  STAGE_HALF(1, 0) STAGE_HALF(1, 1) STAGE_HALF(1, 2)
  vmcnt_wait<6>();  // tile0's 8 loads retired; tile1's 3 halves in flight
  asm volatile("" ::: "memory");
  __builtin_amdgcn_s_barrier();

  f32x4 acc[8][4] = {};
  int rA = wm * 128 + l16;
  int rB = wn * 64 + l16;

  for (int t = 0; t < ntk; t++) {
    const bf16* Ld = &lds[(t & 1) << 15];
    bf16x8 af[8], af2[8], b0, b1, b2, b3;

    // ---- phase 0 ----
#pragma unroll
    for (int mi = 0; mi < 8; mi++) {
      int r = rA + mi * 16;
      af[mi] = *(const bf16x8*)&Ld[r * 32 + (quad ^ ((r >> 1) & 3)) * 8];
    }
    {
      int r = rB;
      b0 = *(const bf16x8*)&Ld[16384 + r * 32 + (quad ^ ((r >> 1) & 3)) * 8];
      r = rB + 16;
      b1 = *(const bf16x8*)&Ld[16384 + r * 32 + (quad ^ ((r >> 1) & 3)) * 8];
    }
    if (t + 1 < ntk) STAGE_HALF(t + 1, 3)
    asm volatile("" ::: "memory");
    __builtin_amdgcn_s_barrier();
    asm volatile("s_waitcnt lgkmcnt(0)" ::: "memory");
    __builtin_amdgcn_s_setprio(1);
#pragma unroll
    for (int mi = 0; mi < 8; mi++)
      acc[mi][0] = __builtin_amdgcn_mfma_f32_16x16x32_bf16(af[mi], b0, acc[mi][0], 0, 0, 0);
#pragma unroll
    for (int mi = 0; mi < 8; mi++)
      acc[mi][1] = __builtin_amdgcn_mfma_f32_16x16x32_bf16(af[mi], b1, acc[mi][1], 0, 0, 0);
    __builtin_amdgcn_s_setprio(0);
    asm volatile("" ::: "memory");
    __builtin_amdgcn_s_barrier();

    // ---- phase 1 ----
    {
      int r = rB + 32;
      b2 = *(const bf16x8*)&Ld[16384 + r * 32 + (quad ^ ((r >> 1) & 3)) * 8];
      r = rB + 48;
      b3 = *(const bf16x8*)&Ld[16384 + r * 32 + (quad ^ ((r >> 1) & 3)) * 8];
    }
#pragma unroll
    for (int mi = 0; mi < 8; mi++) {
      int r = rA + mi * 16;
      af2[mi] = *(const bf16x8*)&Ld[8192 + r * 32 + (quad ^ ((r >> 1) & 3)) * 8];
    }
    if (t + 2 < ntk) STAGE_HALF(t + 2, 0)
    asm volatile("" ::: "memory");
    __builtin_amdgcn_s_barrier();
    asm volatile("s_waitcnt lgkmcnt(0)" ::: "memory");
    __builtin_amdgcn_s_setprio(1);
#pragma unroll
    for (int mi = 0; mi < 8; mi++)
      acc[mi][2] = __builtin_amdgcn_mfma_f32_16x16x32_bf16(af[mi], b2, acc[mi][2], 0, 0, 0);
#pragma unroll
    for (int mi = 0; mi < 8; mi++)
      acc[mi][3] = __builtin_amdgcn_mfma_f32_16x16x32_bf16(af[mi], b3, acc[mi][3], 0, 0, 0);
    __builtin_amdgcn_s_setprio(0);
    asm volatile("" ::: "memory");
    __builtin_amdgcn_s_barrier();

    // ---- phase 2 ----
    {
      int r = rB;
      b0 = *(const bf16x8*)&Ld[24576 + r * 32 + (quad ^ ((r >> 1) & 3)) * 8];
      r = rB + 16;
      b1 = *(const bf16x8*)&Ld[24576 + r * 32 + (quad ^ ((r >> 1) & 3)) * 8];
    }
    if (t + 2 < ntk) STAGE_HALF(t + 2, 1)
    asm volatile("" ::: "memory");
    __builtin_amdgcn_s_barrier();
    asm volatile("s_waitcnt lgkmcnt(0)" ::: "memory");
    __builtin_amdgcn_s_setprio(1);
#pragma unroll
    for (int mi = 0; mi < 8; mi++)
      acc[mi][0] = __builtin_amdgcn_mfma_f32_16x16x32_bf16(af2[mi], b0, acc[mi][0], 0, 0, 0);
#pragma unroll
    for (int mi = 0; mi < 8; mi++)
      acc[mi][1] = __builtin_amdgcn_mfma_f32_16x16x32_bf16(af2[mi], b1, acc[mi][1], 0, 0, 0);
    __builtin_amdgcn_s_setprio(0);
    asm volatile("" ::: "memory");
    __builtin_amdgcn_s_barrier();

    // ---- phase 3 ----
    {
      int r = rB + 32;
      b2 = *(const bf16x8*)&Ld[24576 + r * 32 + (quad ^ ((r >> 1) & 3)) * 8];
      r = rB + 48;
      b3 = *(const bf16x8*)&Ld[24576 + r * 32 + (quad ^ ((r >> 1) & 3)) * 8];
    }
    if (t + 2 < ntk) STAGE_HALF(t + 2, 2)
    vmcnt_wait<6>();  // counted: 3 newest halves may stay in flight
    asm volatile("" ::: "memory");
    __builtin_amdgcn_s_barrier();
    asm volatile("s_waitcnt lgkmcnt(0)" ::: "memory");
    __builtin_amdgcn_s_setprio(1);
#pragma unroll
    for (int mi = 0; mi < 8; mi++)
      acc[mi][2] = __builtin_amdgcn_mfma_f32_16x16x32_bf16(af2[mi], b2, acc[mi][2], 0, 0, 0);
#pragma unroll
    for (int mi = 0; mi < 8; mi++)
      acc[mi][3] = __builtin_amdgcn_mfma_f32_16x16x32_bf16(af2[mi], b3, acc[mi][3], 0, 0, 0);
    __builtin_amdgcn_s_setprio(0);
    asm volatile("" ::: "memory");
    __builtin_amdgcn_s_barrier();
  }
#undef STAGE_HALF

  // epilogue
  int gm = m0 + wm * 128, gn = n0 + wn * 64;
#pragma unroll
  for (int ni = 0; ni < 4; ni++) {
    int col = gn + ni * 16 + l16;
    float bvb = (EPI != 0) ? bias[col] : 0.0f;
#pragma unroll
    for (int mi = 0; mi < 8; mi++) {
#pragma unroll
      for (int r = 0; r < 4; r++) {
        int row = gm + mi * 16 + quad * 4 + r;
        float v = acc[mi][ni][r] + bvb;
        if (EPI == 2) {
          v = 0.5f * v * (1.0f + erff(v * 0.70710678118654752f));
        } else if (EPI == 1) {
          float rv = RBF16 ? (float)((const bf16*)resv)[(long)row * ldr + col]
                           : ((const float*)resv)[(long)row * ldr + col];
          v += rv;
        }
        if (CF32)
          ((float*)Cv)[(long)row * ldc + col] = v;
        else
          ((bf16*)Cv)[(long)row * ldc + col] = (bf16)v;
      }
    }
  }
}

extern "C" void kernel_launch(void* const* d_in, const int* in_sizes, int n_in,
                              void* d_out, int out_size, void* d_ws, size_t ws_size,
                              hipStream_t stream) {
  const float* src_q  = (const float*)d_in[0];
  const float* src_kv = (const float*)d_in[1];
  const float* gq     = (const float*)d_in[2];
  const float* bq     = (const float*)d_in[3];
  const float* gkv    = (const float*)d_in[4];
  const float* bkv    = (const float*)d_in[5];
  const float* Wq     = (const float*)d_in[6];
  const float* Wkv    = (const float*)d_in[7];
  const float* Wproj  = (const float*)d_in[8];
  const float* bproj  = (const float*)d_in[9];
  const float* gn     = (const float*)d_in[10];
  const float* bn     = (const float*)d_in[11];
  const float* W1     = (const float*)d_in[12];
  const float* b1     = (const float*)d_in[13];
  const float* W2     = (const float*)d_in[14];
  const float* b2     = (const float*)d_in[15];
  float* out = (float*)d_out;

  char* ws = (char*)d_ws;
  const long MB = 1024 * 1024;
  bf16* Wq_t    = (bf16*)(ws + 0 * MB);
  bf16* Wkv_t   = (bf16*)(ws + 2 * MB);
  bf16* Wproj_t = (bf16*)(ws + 6 * MB);
  bf16* W1_t    = (bf16*)(ws + 8 * MB);
  bf16* W2_t    = (bf16*)(ws + 16 * MB);
  bf16* qn      = (bf16*)(ws + 24 * MB);
  bf16* kvn     = (bf16*)(ws + 32 * MB);
  bf16* Qm      = (bf16*)(ws + 40 * MB);
  bf16* KVm     = (bf16*)(ws + 48 * MB);
  bf16* Vt      = (bf16*)(ws + 64 * MB);
  bf16* xbuf    = (bf16*)(ws + 24 * MB);
  float* tbuf   = (float*)(ws + 48 * MB);
  bf16* sbuf    = (bf16*)(ws + 64 * MB);
  bf16* hbuf    = (bf16*)(ws + 72 * MB);

  transpose_w<<<dim3(16, 16), 256, 0, stream>>>(Wq, Wq_t, 1024, 1024);
  transpose_w<<<dim3(32, 16), 256, 0, stream>>>(Wkv, Wkv_t, 1024, 2048);
  transpose_w<<<dim3(16, 16), 256, 0, stream>>>(Wproj, Wproj_t, 1024, 1024);
  transpose_w<<<dim3(64, 16), 256, 0, stream>>>(W1, W1_t, 1024, 4096);
  transpose_w<<<dim3(16, 64), 256, 0, stream>>>(W2, W2_t, 4096, 1024);

  ln_f32<<<4096, 256, 0, stream>>>(src_q, gq, bq, qn);
  ln_f32<<<4096, 256, 0, stream>>>(src_kv, gkv, bkv, kvn);

  // Q = qn @ Wq: 128x128, 256 blocks
  gemm_p<128, 128, 2, 4, 0, 0, 0><<<dim3(8, 32), 512, 0, stream>>>(
      qn, 1024, Wq_t, 1024, Qm, 1024, 1024, nullptr, nullptr, 0);
  // KV = kvn @ Wkv: 256x128, 256 blocks
  gemm_p<256, 128, 4, 2, 0, 0, 0><<<dim3(16, 16), 512, 0, stream>>>(
      kvn, 1024, Wkv_t, 1024, KVm, 2048, 1024, nullptr, nullptr, 0);
  extract_vt<<<dim3(16, 1, 64), 256, 0, stream>>>(KVm, Vt);

  attn_fused<<<dim3(8, 64), 256, 0, stream>>>(Qm, KVm, Vt, xbuf);

  // tbuf = src_q + x @ Wproj + bproj
  gemm_p<128, 128, 2, 4, 1, 1, 0><<<dim3(8, 32), 512, 0, stream>>>(
      xbuf, 1024, Wproj_t, 1024, tbuf, 1024, 1024, bproj, src_q, 1024);
  ln_f32<<<4096, 256, 0, stream>>>(tbuf, gn, bn, sbuf);
  // hbuf = gelu(sbuf @ W1 + b1): 8-phase 256x256, 256 blocks (1/CU)
  gemm_8p<2, 0, 0><<<dim3(16, 16), 512, 0, stream>>>(
      sbuf, 1024, W1_t, 1024, hbuf, 4096, 1024, b1, nullptr, 0);
  // out = sbuf + hbuf @ W2 + b2: 128x128, 256 blocks
  gemm_p<128, 128, 2, 4, 1, 1, 1><<<dim3(8, 32), 512, 0, stream>>>(
      hbuf, 4096, W2_t, 4096, out, 1024, 4096, b2, sbuf, 1024);
}

// Round 8
// 358.123 us; speedup vs baseline: 1.0256x; 1.0256x over previous
//
#include <hip/hip_runtime.h>
#include <hip/hip_bf16.h>
#include <math.h>

typedef __bf16 bf16;
typedef __bf16 bf16x2 __attribute__((ext_vector_type(2)));
typedef __bf16 bf16x8 __attribute__((ext_vector_type(8)));
typedef float f32x4 __attribute__((ext_vector_type(4)));
typedef float f32x16 __attribute__((ext_vector_type(16)));
typedef unsigned int u32;
typedef unsigned int u32x2 __attribute__((ext_vector_type(2)));
typedef unsigned int u32x4 __attribute__((ext_vector_type(4)));

#define SCALE 0.125f

// async global->LDS, 16B per lane. LDS dest must be wave-uniform base + lane*16.
#define GLOAD_LDS16(gptr, lptr)                                      \
  __builtin_amdgcn_global_load_lds(                                  \
      (const __attribute__((address_space(1))) void*)(gptr),         \
      (__attribute__((address_space(3))) void*)(lptr), 16, 0, 0)

template <int N>
__device__ __forceinline__ void vmcnt_wait() {
  if constexpr (N == 0) asm volatile("s_waitcnt vmcnt(0)" ::: "memory");
  else if constexpr (N == 4) asm volatile("s_waitcnt vmcnt(4)" ::: "memory");
  else if constexpr (N == 6) asm volatile("s_waitcnt vmcnt(6)" ::: "memory");
  else static_assert(N == 0 || N == 4 || N == 6, "unsupported vmcnt");
}

// XCD-chunked bijective block swizzle (T1). Bijective for gx%8==0, nwg%8==0.
__device__ __forceinline__ void xcd_swz(int gx, int gy, int& x, int& y) {
  int w = blockIdx.x + gx * blockIdx.y;
  int nwg = gx * gy;
  int wp = (w & 7) * (nwg >> 3) + (w >> 3);
  int xi = wp & 7;
  int t = wp >> 3;
  y = t % gy;
  x = (t / gy) * 8 + xi;
}

// pack two f32 -> one u32 of 2 bf16 (RNE)
__device__ __forceinline__ u32 pk_bf16(float lo, float hi) {
  bf16x2 t;
  t[0] = (bf16)lo;
  t[1] = (bf16)hi;
  return __builtin_bit_cast(u32, t);
}

// v_permlane32_swap_b32: a.hi <-> b.lo
__device__ __forceinline__ void plane32_swap(u32& a, u32& b) {
  asm volatile("v_permlane32_swap_b32 %0, %1" : "+v"(a), "+v"(b));
}

// ---------------- row LayerNorm: fp32 in -> bf16 out ----------------
__global__ __launch_bounds__(256) void ln_f32(const float* __restrict__ x,
                                              const float* __restrict__ g,
                                              const float* __restrict__ b,
                                              bf16* __restrict__ y) {
  long base = (long)blockIdx.x * 1024;
  int tid = threadIdx.x;
  float v[4];
#pragma unroll
  for (int i = 0; i < 4; i++) v[i] = x[base + tid + i * 256];
  float s1 = v[0] + v[1] + v[2] + v[3];
  float s2 = v[0] * v[0] + v[1] * v[1] + v[2] * v[2] + v[3] * v[3];
#pragma unroll
  for (int off = 32; off; off >>= 1) {
    s1 += __shfl_xor(s1, off);
    s2 += __shfl_xor(s2, off);
  }
  __shared__ float aux[2][4];
  int wave = tid >> 6, lane = tid & 63;
  if (lane == 0) { aux[0][wave] = s1; aux[1][wave] = s2; }
  __syncthreads();
  float S1 = aux[0][0] + aux[0][1] + aux[0][2] + aux[0][3];
  float S2 = aux[1][0] + aux[1][1] + aux[1][2] + aux[1][3];
  float mean = S1 * (1.0f / 1024.0f);
  float var = S2 * (1.0f / 1024.0f) - mean * mean;
  float rs = rsqrtf(var + 1e-5f);
#pragma unroll
  for (int i = 0; i < 4; i++) {
    int c = tid + i * 256;
    y[base + c] = (bf16)(((v[i] - mean) * rs) * g[c] + b[c]);
  }
}

// ---------------- W[K][N] fp32 -> Wt[N][K] bf16 tiled transpose ----------------
__global__ __launch_bounds__(256) void transpose_w(const float* __restrict__ W,
                                                   bf16* __restrict__ Wt,
                                                   int K, int N) {
  __shared__ bf16 tile[64][66];
  int n0 = blockIdx.x * 64, k0 = blockIdx.y * 64;
  int c = threadIdx.x & 63, r4 = threadIdx.x >> 6;
#pragma unroll
  for (int i = 0; i < 16; i++)
    tile[i * 4 + r4][c] = (bf16)W[(long)(k0 + i * 4 + r4) * N + n0 + c];
  __syncthreads();
#pragma unroll
  for (int i = 0; i < 16; i++)
    Wt[(long)(n0 + i * 4 + r4) * K + k0 + c] = tile[c][i * 4 + r4];
}

// ------- extract V^T per (b,h) -------
__global__ __launch_bounds__(256) void extract_vt(const bf16* __restrict__ KV,
                                                  bf16* __restrict__ Vt) {
  __shared__ bf16 tile[64][66];
  int bh = blockIdx.z, b = bh >> 4, h = bh & 15;
  const bf16* src = KV + (long)b * 1024 * 2048 + 1024 + h * 64;
  bf16* dst = Vt + (long)bh * 64 * 1024;
  int n0 = blockIdx.x * 64;
  int c = threadIdx.x & 63, r4 = threadIdx.x >> 6;
#pragma unroll
  for (int i = 0; i < 16; i++)
    tile[i * 4 + r4][c] = src[(long)(n0 + i * 4 + r4) * 2048 + c];
  __syncthreads();
#pragma unroll
  for (int i = 0; i < 16; i++)
    dst[(long)(i * 4 + r4) * 1024 + n0 + c] = tile[c][i * 4 + r4];
}

// ---------------- fused flash attention, swapped-QK^T in-register softmax ----------------
__global__ __launch_bounds__(256) void attn_fused(
    const bf16* __restrict__ Q,   // [4096][1024]
    const bf16* __restrict__ KV,  // [4096][2048], K at col h*64
    const bf16* __restrict__ Vt,  // [64 bh][64 d][1024 n]
    bf16* __restrict__ X) {       // [4096][1024]
  __shared__ __align__(16) bf16 Qs[128 * 64];
  __shared__ __align__(16) bf16 Ks[2][64 * 128];
  __shared__ __align__(16) bf16 Vs[2][64 * 128];
  int tid = threadIdx.x, wave = tid >> 6, lane = tid & 63;
  int l31 = lane & 31, h = lane >> 5;
  int bqx, bhy;
  xcd_swz(8, 64, bqx, bhy);
  int bh = bhy, b = bh >> 4, hd = bh & 15;
  const bf16* Qb = Q + (long)b * 1048576 + hd * 64;
  const bf16* Kb = KV + (long)b * 2097152 + hd * 64;
  const bf16* Vb = Vt + (long)bh * 65536;
  bf16* Xb = X + (long)b * 1048576 + hd * 64;
  int q0 = bqx * 128;

  const bf16* gk[4];
  const bf16* gv[4];
  int eoKV[4];
#pragma unroll
  for (int t = 0; t < 4; t++) {
    int eo = (t * 256 + tid) * 8;
    eoKV[t] = eo;
    int r2 = eo >> 7, pp = (eo & 127) >> 3, q = pp ^ (r2 & 15);
    gk[t] = &Kb[(long)(r2 + ((q >> 3) << 6)) * 2048 + ((q & 7) << 3)];
    gv[t] = &Vb[(long)r2 * 1024 + (q << 3)];
  }

#pragma unroll
  for (int t = 0; t < 4; t++) {
    int eo = (t * 256 + tid) * 8;
    int r = eo >> 6, p = (eo & 63) >> 3;
    int c = (p ^ (r & 7)) << 3;
    GLOAD_LDS16(&Qb[(long)(q0 + r) * 1024 + c], &Qs[eo]);
  }
#pragma unroll
  for (int t = 0; t < 4; t++) GLOAD_LDS16(gk[t], &Ks[0][eoKV[t]]);
#pragma unroll
  for (int t = 0; t < 4; t++) GLOAD_LDS16(gv[t], &Vs[0][eoKV[t]]);
  __syncthreads();

  bf16x8 qf[4];
  {
    int r = wave * 32 + l31;
#pragma unroll
    for (int dw = 0; dw < 4; dw++) {
      int p = (dw * 2 + h) ^ (r & 7);
      qf[dw] = *(const bf16x8*)&Qs[r * 64 + p * 8];
    }
  }

  const float C = 0.18033688011112042f;  // SCALE * log2(e)
  float m_run = -1e30f, l_run = 0.0f;
  f32x16 acc[2] = {};
  int cur = 0;

  for (int kc = 0; kc < 8; kc++) {
    if (kc < 7) {
#pragma unroll
      for (int t = 0; t < 4; t++)
        GLOAD_LDS16(gk[t] + (long)(kc + 1) * 128 * 2048, &Ks[cur ^ 1][eoKV[t]]);
#pragma unroll
      for (int t = 0; t < 4; t++)
        GLOAD_LDS16(gv[t] + (kc + 1) * 128, &Vs[cur ^ 1][eoKV[t]]);
    }
    const bf16* ks = Ks[cur];
    const bf16* vs = Vs[cur];

    f32x16 s[4] = {};
#pragma unroll
    for (int kt = 0; kt < 4; kt++) {
      int k = kt * 32 + l31;
      int r2 = k & 63, hi = k >> 6;
#pragma unroll
      for (int dw = 0; dw < 4; dw++) {
        int p = (hi * 8 + dw * 2 + h) ^ (r2 & 15);
        bf16x8 kf = *(const bf16x8*)&ks[r2 * 128 + p * 8];
        s[kt] = __builtin_amdgcn_mfma_f32_32x32x16_bf16(kf, qf[dw], s[kt], 0, 0, 0);
      }
    }

    float mk[4];
#pragma unroll
    for (int kt = 0; kt < 4; kt++) {
      float m01 = fmaxf(fmaxf(s[kt][0], s[kt][1]), fmaxf(s[kt][2], s[kt][3]));
      float m23 = fmaxf(fmaxf(s[kt][4], s[kt][5]), fmaxf(s[kt][6], s[kt][7]));
      float m45 = fmaxf(fmaxf(s[kt][8], s[kt][9]), fmaxf(s[kt][10], s[kt][11]));
      float m67 = fmaxf(fmaxf(s[kt][12], s[kt][13]), fmaxf(s[kt][14], s[kt][15]));
      mk[kt] = fmaxf(fmaxf(m01, m23), fmaxf(m45, m67));
    }
    float mx = fmaxf(fmaxf(mk[0], mk[1]), fmaxf(mk[2], mk[3]));
    mx = fmaxf(mx, __shfl_xor(mx, 32));
    float m_new = fmaxf(m_run, mx);
    float alpha = exp2f((m_run - m_new) * C);
    m_run = m_new;
    float mc = m_new * C;
    float rk[4];
#pragma unroll
    for (int kt = 0; kt < 4; kt++) {
      float r0 = 0.0f;
#pragma unroll
      for (int r = 0; r < 16; r++) {
        float pv = exp2f(s[kt][r] * C - mc);
        s[kt][r] = pv;
        r0 += pv;
      }
      rk[kt] = r0;
    }
    float rs = (rk[0] + rk[1]) + (rk[2] + rk[3]);
    rs += __shfl_xor(rs, 32);
    l_run = l_run * alpha + rs;
#pragma unroll
    for (int nt = 0; nt < 2; nt++)
#pragma unroll
      for (int r = 0; r < 16; r++) acc[nt][r] *= alpha;

#pragma unroll
    for (int kw = 0; kw < 8; kw++) {
      int kt = kw >> 1, rb = (kw & 1) * 8;
      u32 wA = pk_bf16(s[kt][rb + 0], s[kt][rb + 1]);
      u32 wB = pk_bf16(s[kt][rb + 2], s[kt][rb + 3]);
      u32 wC = pk_bf16(s[kt][rb + 4], s[kt][rb + 5]);
      u32 wD = pk_bf16(s[kt][rb + 6], s[kt][rb + 7]);
      plane32_swap(wA, wC);
      plane32_swap(wB, wD);
      u32x4 wv = {wA, wB, wC, wD};
      bf16x8 pf = __builtin_bit_cast(bf16x8, wv);
#pragma unroll
      for (int nt = 0; nt < 2; nt++) {
        int r2 = nt * 32 + l31;
        int p = (kw * 2 + h) ^ (r2 & 15);
        bf16x8 vf = *(const bf16x8*)&vs[r2 * 128 + p * 8];
        acc[nt] = __builtin_amdgcn_mfma_f32_32x32x16_bf16(vf, pf, acc[nt], 0, 0, 0);
      }
    }

    if (kc < 7) {
      __syncthreads();
      cur ^= 1;
    }
  }

  float fs = SCALE / l_run;
  bf16* Os = Qs;
  int qrow = wave * 32 + l31;
#pragma unroll
  for (int nt = 0; nt < 2; nt++)
#pragma unroll
    for (int g = 0; g < 4; g++) {
      u32 w0 = pk_bf16(acc[nt][g * 4 + 0] * fs, acc[nt][g * 4 + 1] * fs);
      u32 w1 = pk_bf16(acc[nt][g * 4 + 2] * fs, acc[nt][g * 4 + 3] * fs);
      int s8 = nt * 8 + g * 2 + h;
      int phys = s8 ^ (qrow & 15);
      u32x2 wv = {w0, w1};
      *(u32x2*)&Os[qrow * 64 + phys * 4] = wv;
    }
  int rrow = wave * 32 + (lane >> 1);
  int cbase = (lane & 1) * 32;
#pragma unroll
  for (int t2 = 0; t2 < 4; t2++) {
    int s0 = (lane & 1) * 8 + t2 * 2;
    u32x2 a = *(u32x2*)&Os[rrow * 64 + ((s0 ^ (rrow & 15)) * 4)];
    u32x2 bb = *(u32x2*)&Os[rrow * 64 + (((s0 + 1) ^ (rrow & 15)) * 4)];
    u32x4 o4 = {a[0], a[1], bb[0], bb[1]};
    *(u32x4*)&Xb[(long)(q0 + rrow) * 1024 + cbase + t2 * 8] = o4;
  }
}

// ---------------- pipelined gemm_p (R3-best pinned body), triple-buffered, 512 thr ----------------
template <int BM, int BN, int WR, int WC, int EPI, int CF32, int RBF16>
__global__ __launch_bounds__(512) void gemm_p(
    const bf16* __restrict__ A, int lda,
    const bf16* __restrict__ B, int ldb,
    void* __restrict__ Cv, int ldc, int K,
    const float* __restrict__ bias,
    const void* __restrict__ resv, int ldr) {
  constexpr int MT = BM / (16 * WR);
  constexpr int NT = BN / (16 * WC);
  constexpr int L = (BM + BN) / 64;
  constexpr int LA = BM / 64;
  constexpr int AE = BM * 64;
  constexpr int BUFE = (BM + BN) * 64;
  __shared__ __align__(16) bf16 lds[3 * BUFE];
  int tid = threadIdx.x;
  int wave = tid >> 6, lane = tid & 63;
  int wm = wave / WC, wn = wave % WC;
  int quad = lane >> 4, l16 = lane & 15;
  int bx, by;
  xcd_swz(gridDim.x, gridDim.y, bx, by);
  int m0 = by * BM, n0 = bx * BN;

  const bf16* gp[L];
  int lo[L];
#pragma unroll
  for (int i = 0; i < L; i++) {
    if (i < LA) {
      int eo = (i * 512 + tid) * 8;
      int r = eo >> 6, p = (eo & 63) >> 3;
      int c = (p ^ (r & 7)) << 3;
      gp[i] = &A[(long)(m0 + r) * lda + c];
      lo[i] = eo;
    } else {
      int eo = ((i - LA) * 512 + tid) * 8;
      int r = eo >> 6, p = (eo & 63) >> 3;
      int c = (p ^ (r & 7)) << 3;
      gp[i] = &B[(long)(n0 + r) * ldb + c];
      lo[i] = AE + eo;
    }
  }

  int ntk = K >> 6;
#pragma unroll
  for (int i = 0; i < L; i++) GLOAD_LDS16(gp[i], &lds[lo[i]]);
#pragma unroll
  for (int i = 0; i < L; i++) gp[i] += 64;
#pragma unroll
  for (int i = 0; i < L; i++) GLOAD_LDS16(gp[i], &lds[BUFE + lo[i]]);
#pragma unroll
  for (int i = 0; i < L; i++) gp[i] += 64;
  vmcnt_wait<L>();
  asm volatile("" ::: "memory");
  __builtin_amdgcn_s_barrier();

  f32x4 acc[MT][NT] = {};
  int b = 0;
  for (int t = 0; t < ntk; t++) {
    const bf16* Al = &lds[b * BUFE];
    const bf16* Bl = &lds[b * BUFE + AE];
    int b2 = b + 2; if (b2 >= 3) b2 -= 3;
    bool more = (t + 2) < ntk;

    bf16x8 af[2][MT], bv[2][NT];
#pragma unroll
    for (int ks = 0; ks < 2; ks++) {
#pragma unroll
      for (int mt = 0; mt < MT; mt++) {
        int row = wm * (BM / WR) + mt * 16 + l16;
        int p = (ks * 4 + quad) ^ (row & 7);
        af[ks][mt] = *(const bf16x8*)&Al[row * 64 + p * 8];
      }
#pragma unroll
      for (int nt = 0; nt < NT; nt++) {
        int row = wn * (BN / WC) + nt * 16 + l16;
        int p = (ks * 4 + quad) ^ (row & 7);
        bv[ks][nt] = *(const bf16x8*)&Bl[row * 64 + p * 8];
      }
    }
    if (more) {
#pragma unroll
      for (int i = 0; i < L; i++) GLOAD_LDS16(gp[i], &lds[b2 * BUFE + lo[i]]);
    }
    asm volatile("s_waitcnt lgkmcnt(0)" ::: "memory");
    __builtin_amdgcn_sched_barrier(0);
    __builtin_amdgcn_s_setprio(1);
#pragma unroll
    for (int ks = 0; ks < 2; ks++)
#pragma unroll
      for (int mt = 0; mt < MT; mt++)
#pragma unroll
        for (int nt = 0; nt < NT; nt++)
          acc[mt][nt] = __builtin_amdgcn_mfma_f32_16x16x32_bf16(
              af[ks][mt], bv[ks][nt], acc[mt][nt], 0, 0, 0);
    __builtin_amdgcn_s_setprio(0);
    __builtin_amdgcn_sched_barrier(0);
    if (more) {
      vmcnt_wait<L>();
    } else if (t + 1 < ntk) {
      vmcnt_wait<0>();
    }
    if (t + 1 < ntk) {
      asm volatile("" ::: "memory");
      __builtin_amdgcn_s_barrier();
    }
#pragma unroll
    for (int i = 0; i < L; i++) gp[i] += 64;
    b += 1; if (b == 3) b = 0;
  }

  int gm = m0 + wm * (BM / WR), gn = n0 + wn * (BN / WC);
#pragma unroll
  for (int nt = 0; nt < NT; nt++) {
    int col = gn + nt * 16 + l16;
    float bvb = (EPI != 0) ? bias[col] : 0.0f;
#pragma unroll
    for (int mt = 0; mt < MT; mt++) {
#pragma unroll
      for (int r = 0; r < 4; r++) {
        int row = gm + mt * 16 + quad * 4 + r;
        float v = acc[mt][nt][r] + bvb;
        if (EPI == 2) {
          v = 0.5f * v * (1.0f + erff(v * 0.70710678118654752f));
        } else if (EPI == 1) {
          float rv = RBF16 ? (float)((const bf16*)resv)[(long)row * ldr + col]
                           : ((const float*)resv)[(long)row * ldr + col];
          v += rv;
        }
        if (CF32)
          ((float*)Cv)[(long)row * ldc + col] = v;
        else
          ((bf16*)Cv)[(long)row * ldc + col] = (bf16)v;
      }
    }
  }
}

// ---------------- gemm_d: 128x128, 256 thr (4 waves), double-buffered, 2 blocks/CU ----------------
// The co-residency kernel (m114/m103 mechanism): 64 KB LDS -> 2 blocks/CU, so
// while one block drains vmcnt(0) at its barrier, the OTHER block's waves keep
// the MFMA pipe fed. Body = R3-proven pinned form: stage(t+1) early -> frag
// ds_reads -> lgkmcnt(0) -> sched_barrier -> setprio MFMA x32 -> vmcnt(0) ->
// barrier. Ledger: tile t reads buf[t&1]; stage t+1 -> buf[(t+1)&1] issued
// after tile t-1's closing barrier (all reads of that buffer retired at each
// wave's lgkmcnt(0) before that barrier) -> no write-before-read; vmcnt(0)+
// barrier at tile end makes t+1 resident before its reads. Per-wave C = 64x64.
template <int EPI, int CF32, int RBF16>
__global__ __launch_bounds__(256, 2) void gemm_d(
    const bf16* __restrict__ A, int lda,
    const bf16* __restrict__ B, int ldb,
    void* __restrict__ Cv, int ldc, int K,
    const float* __restrict__ bias,
    const void* __restrict__ resv, int ldr) {
  constexpr int AE = 128 * 64;          // 8192 elems
  constexpr int BUFE = 256 * 64;        // A+B tile = 32 KB
  __shared__ __align__(16) bf16 lds[2 * BUFE];  // 64 KB -> 2 blocks/CU
  int tid = threadIdx.x;
  int wave = tid >> 6, lane = tid & 63;
  int wm = wave >> 1, wn = wave & 1;    // 2x2 wave grid, per-wave 64x64
  int quad = lane >> 4, l16 = lane & 15;
  int bx, by;
  xcd_swz(gridDim.x, gridDim.y, bx, by);
  int m0 = by * 128, n0 = bx * 128;

  // 8 gloads/thread/tile (A 4, B 4); dest linear, source inverse-swizzled
  const bf16* gp[8];
  int lo[8];
#pragma unroll
  for (int i = 0; i < 8; i++) {
    if (i < 4) {
      int eo = (i * 256 + tid) * 8;
      int r = eo >> 6, p = (eo & 63) >> 3;
      int c = (p ^ (r & 7)) << 3;
      gp[i] = &A[(long)(m0 + r) * lda + c];
      lo[i] = eo;
    } else {
      int eo = ((i - 4) * 256 + tid) * 8;
      int r = eo >> 6, p = (eo & 63) >> 3;
      int c = (p ^ (r & 7)) << 3;
      gp[i] = &B[(long)(n0 + r) * ldb + c];
      lo[i] = AE + eo;
    }
  }

  int ntk = K >> 6;
  // prologue: stage tile 0 -> buf0
#pragma unroll
  for (int i = 0; i < 8; i++) GLOAD_LDS16(gp[i], &lds[lo[i]]);
#pragma unroll
  for (int i = 0; i < 8; i++) gp[i] += 64;
  vmcnt_wait<0>();
  asm volatile("" ::: "memory");
  __builtin_amdgcn_s_barrier();

  f32x4 acc[4][4] = {};
  for (int t = 0; t < ntk; t++) {
    const bf16* Al = &lds[(t & 1) * BUFE];
    const bf16* Bl = &lds[(t & 1) * BUFE + AE];
    // stage tile t+1 early (a full tile body of latency cover)
    if (t + 1 < ntk) {
#pragma unroll
      for (int i = 0; i < 8; i++)
        GLOAD_LDS16(gp[i], &lds[((t + 1) & 1) * BUFE + lo[i]]);
#pragma unroll
      for (int i = 0; i < 8; i++) gp[i] += 64;
    }
    bf16x8 af[2][4], bv[2][4];
#pragma unroll
    for (int ks = 0; ks < 2; ks++) {
#pragma unroll
      for (int mt = 0; mt < 4; mt++) {
        int row = wm * 64 + mt * 16 + l16;
        int p = (ks * 4 + quad) ^ (row & 7);
        af[ks][mt] = *(const bf16x8*)&Al[row * 64 + p * 8];
      }
#pragma unroll
      for (int nt = 0; nt < 4; nt++) {
        int row = wn * 64 + nt * 16 + l16;
        int p = (ks * 4 + quad) ^ (row & 7);
        bv[ks][nt] = *(const bf16x8*)&Bl[row * 64 + p * 8];
      }
    }
    asm volatile("s_waitcnt lgkmcnt(0)" ::: "memory");
    __builtin_amdgcn_sched_barrier(0);
    __builtin_amdgcn_s_setprio(1);
#pragma unroll
    for (int ks = 0; ks < 2; ks++)
#pragma unroll
      for (int mt = 0; mt < 4; mt++)
#pragma unroll
        for (int nt = 0; nt < 4; nt++)
          acc[mt][nt] = __builtin_amdgcn_mfma_f32_16x16x32_bf16(
              af[ks][mt], bv[ks][nt], acc[mt][nt], 0, 0, 0);
    __builtin_amdgcn_s_setprio(0);
    __builtin_amdgcn_sched_barrier(0);
    if (t + 1 < ntk) {
      vmcnt_wait<0>();  // drain ok: co-resident block hides it (m114)
      asm volatile("" ::: "memory");
      __builtin_amdgcn_s_barrier();
    }
  }

  // epilogue
  int gm = m0 + wm * 64, gn = n0 + wn * 64;
#pragma unroll
  for (int nt = 0; nt < 4; nt++) {
    int col = gn + nt * 16 + l16;
    float bvb = (EPI != 0) ? bias[col] : 0.0f;
#pragma unroll
    for (int mt = 0; mt < 4; mt++) {
#pragma unroll
      for (int r = 0; r < 4; r++) {
        int row = gm + mt * 16 + quad * 4 + r;
        float v = acc[mt][nt][r] + bvb;
        if (EPI == 2) {
          v = 0.5f * v * (1.0f + erff(v * 0.70710678118654752f));
        } else if (EPI == 1) {
          float rv = RBF16 ? (float)((const bf16*)resv)[(long)row * ldr + col]
                           : ((const float*)resv)[(long)row * ldr + col];
          v += rv;
        }
        if (CF32)
          ((float*)Cv)[(long)row * ldc + col] = v;
        else
          ((bf16*)Cv)[(long)row * ldc + col] = (bf16)v;
      }
    }
  }
}

extern "C" void kernel_launch(void* const* d_in, const int* in_sizes, int n_in,
                              void* d_out, int out_size, void* d_ws, size_t ws_size,
                              hipStream_t stream) {
  const float* src_q  = (const float*)d_in[0];
  const float* src_kv = (const float*)d_in[1];
  const float* gq     = (const float*)d_in[2];
  const float* bq     = (const float*)d_in[3];
  const float* gkv    = (const float*)d_in[4];
  const float* bkv    = (const float*)d_in[5];
  const float* Wq     = (const float*)d_in[6];
  const float* Wkv    = (const float*)d_in[7];
  const float* Wproj  = (const float*)d_in[8];
  const float* bproj  = (const float*)d_in[9];
  const float* gn     = (const float*)d_in[10];
  const float* bn     = (const float*)d_in[11];
  const float* W1     = (const float*)d_in[12];
  const float* b1     = (const float*)d_in[13];
  const float* W2     = (const float*)d_in[14];
  const float* b2     = (const float*)d_in[15];
  float* out = (float*)d_out;

  char* ws = (char*)d_ws;
  const long MB = 1024 * 1024;
  bf16* Wq_t    = (bf16*)(ws + 0 * MB);
  bf16* Wkv_t   = (bf16*)(ws + 2 * MB);
  bf16* Wproj_t = (bf16*)(ws + 6 * MB);
  bf16* W1_t    = (bf16*)(ws + 8 * MB);
  bf16* W2_t    = (bf16*)(ws + 16 * MB);
  bf16* qn      = (bf16*)(ws + 24 * MB);
  bf16* kvn     = (bf16*)(ws + 32 * MB);
  bf16* Qm      = (bf16*)(ws + 40 * MB);
  bf16* KVm     = (bf16*)(ws + 48 * MB);
  bf16* Vt      = (bf16*)(ws + 64 * MB);
  bf16* xbuf    = (bf16*)(ws + 24 * MB);
  float* tbuf   = (float*)(ws + 48 * MB);
  bf16* sbuf    = (bf16*)(ws + 64 * MB);
  bf16* hbuf    = (bf16*)(ws + 72 * MB);

  transpose_w<<<dim3(16, 16), 256, 0, stream>>>(Wq, Wq_t, 1024, 1024);
  transpose_w<<<dim3(32, 16), 256, 0, stream>>>(Wkv, Wkv_t, 1024, 2048);
  transpose_w<<<dim3(16, 16), 256, 0, stream>>>(Wproj, Wproj_t, 1024, 1024);
  transpose_w<<<dim3(64, 16), 256, 0, stream>>>(W1, W1_t, 1024, 4096);
  transpose_w<<<dim3(16, 64), 256, 0, stream>>>(W2, W2_t, 4096, 1024);

  ln_f32<<<4096, 256, 0, stream>>>(src_q, gq, bq, qn);
  ln_f32<<<4096, 256, 0, stream>>>(src_kv, gkv, bkv, kvn);

  // Q = qn @ Wq: 128x128 gemm_p, 256 blocks
  gemm_p<128, 128, 2, 4, 0, 0, 0><<<dim3(8, 32), 512, 0, stream>>>(
      qn, 1024, Wq_t, 1024, Qm, 1024, 1024, nullptr, nullptr, 0);
  // KV = kvn @ Wkv: gemm_d 128x128, 512 blocks -> 2/CU
  gemm_d<0, 0, 0><<<dim3(16, 32), 256, 0, stream>>>(
      kvn, 1024, Wkv_t, 1024, KVm, 2048, 1024, nullptr, nullptr, 0);
  extract_vt<<<dim3(16, 1, 64), 256, 0, stream>>>(KVm, Vt);

  attn_fused<<<dim3(8, 64), 256, 0, stream>>>(Qm, KVm, Vt, xbuf);

  // tbuf = src_q + x @ Wproj + bproj
  gemm_p<128, 128, 2, 4, 1, 1, 0><<<dim3(8, 32), 512, 0, stream>>>(
      xbuf, 1024, Wproj_t, 1024, tbuf, 1024, 1024, bproj, src_q, 1024);
  ln_f32<<<4096, 256, 0, stream>>>(tbuf, gn, bn, sbuf);
  // hbuf = gelu(sbuf @ W1 + b1): gemm_d 128x128, 1024 blocks -> 2/CU
  gemm_d<2, 0, 0><<<dim3(32, 32), 256, 0, stream>>>(
      sbuf, 1024, W1_t, 1024, hbuf, 4096, 1024, b1, nullptr, 0);
  // out = sbuf + hbuf @ W2 + b2: gemm_p, 256 blocks
  gemm_p<128, 128, 2, 4, 1, 1, 1><<<dim3(8, 32), 512, 0, stream>>>(
      hbuf, 4096, W2_t, 4096, out, 1024, 4096, b2, sbuf, 1024);
}

// Round 9
// 338.608 us; speedup vs baseline: 1.0847x; 1.0576x over previous
//
#include <hip/hip_runtime.h>
#include <hip/hip_bf16.h>
#include <math.h>

typedef __bf16 bf16;
typedef __bf16 bf16x2 __attribute__((ext_vector_type(2)));
typedef __bf16 bf16x4 __attribute__((ext_vector_type(4)));
typedef __bf16 bf16x8 __attribute__((ext_vector_type(8)));
typedef float f32x4 __attribute__((ext_vector_type(4)));
typedef float f32x16 __attribute__((ext_vector_type(16)));
typedef unsigned int u32;
typedef unsigned int u32x2 __attribute__((ext_vector_type(2)));
typedef unsigned int u32x4 __attribute__((ext_vector_type(4)));

#define SCALE 0.125f

// async global->LDS, 16B per lane. LDS dest must be wave-uniform base + lane*16.
#define GLOAD_LDS16(gptr, lptr)                                      \
  __builtin_amdgcn_global_load_lds(                                  \
      (const __attribute__((address_space(1))) void*)(gptr),         \
      (__attribute__((address_space(3))) void*)(lptr), 16, 0, 0)

template <int N>
__device__ __forceinline__ void vmcnt_wait() {
  if constexpr (N == 0) asm volatile("s_waitcnt vmcnt(0)" ::: "memory");
  else if constexpr (N == 4) asm volatile("s_waitcnt vmcnt(4)" ::: "memory");
  else if constexpr (N == 6) asm volatile("s_waitcnt vmcnt(6)" ::: "memory");
  else static_assert(N == 0 || N == 4 || N == 6, "unsupported vmcnt");
}

// XCD-chunked bijective block swizzle (T1). Bijective for gx%8==0, nwg%8==0.
__device__ __forceinline__ void xcd_swz(int gx, int gy, int& x, int& y) {
  int w = blockIdx.x + gx * blockIdx.y;
  int nwg = gx * gy;
  int wp = (w & 7) * (nwg >> 3) + (w >> 3);
  int xi = wp & 7;
  int t = wp >> 3;
  y = t % gy;
  x = (t / gy) * 8 + xi;
}

// pack two f32 -> one u32 of 2 bf16 (RNE)
__device__ __forceinline__ u32 pk_bf16(float lo, float hi) {
  bf16x2 t;
  t[0] = (bf16)lo;
  t[1] = (bf16)hi;
  return __builtin_bit_cast(u32, t);
}

// v_permlane32_swap_b32: a.hi <-> b.lo
__device__ __forceinline__ void plane32_swap(u32& a, u32& b) {
  asm volatile("v_permlane32_swap_b32 %0, %1" : "+v"(a), "+v"(b));
}

// ---------------- merged prologue: 5 weight transposes + 2 LayerNorms, ONE dispatch ----------------
// blocks [0,3072): fp32->bf16 tiled transpose (Wq 256, Wkv 512, Wproj 256, W1 1024, W2 1024)
// blocks [3072,11264): row-LN fp32->bf16 (src_q rows 0..4095, src_kv rows 4096..8191)
__global__ __launch_bounds__(256) void prologue(
    const float* __restrict__ Wq, const float* __restrict__ Wkv,
    const float* __restrict__ Wproj, const float* __restrict__ W1,
    const float* __restrict__ W2,
    bf16* __restrict__ Wq_t, bf16* __restrict__ Wkv_t,
    bf16* __restrict__ Wproj_t, bf16* __restrict__ W1_t,
    bf16* __restrict__ W2_t,
    const float* __restrict__ src_q, const float* __restrict__ src_kv,
    const float* __restrict__ gq, const float* __restrict__ bq,
    const float* __restrict__ gkv, const float* __restrict__ bkv,
    bf16* __restrict__ qn, bf16* __restrict__ kvn) {
  __shared__ bf16 tile[64][66];
  __shared__ float aux[2][4];
  int id = blockIdx.x;
  int tid = threadIdx.x;
  if (id < 3072) {
    const float* W;
    bf16* Wt;
    int K, N, base, tx;
    if (id < 256)       { W = Wq;    Wt = Wq_t;    K = 1024; N = 1024; base = 0;    tx = 16; }
    else if (id < 768)  { W = Wkv;   Wt = Wkv_t;   K = 1024; N = 2048; base = 256;  tx = 32; }
    else if (id < 1024) { W = Wproj; Wt = Wproj_t; K = 1024; N = 1024; base = 768;  tx = 16; }
    else if (id < 2048) { W = W1;    Wt = W1_t;    K = 1024; N = 4096; base = 1024; tx = 64; }
    else                { W = W2;    Wt = W2_t;    K = 4096; N = 1024; base = 2048; tx = 16; }
    int lid = id - base;
    int n0 = (lid % tx) * 64, k0 = (lid / tx) * 64;
    int c = tid & 63, r4 = tid >> 6;
#pragma unroll
    for (int i = 0; i < 16; i++)
      tile[i * 4 + r4][c] = (bf16)W[(long)(k0 + i * 4 + r4) * N + n0 + c];
    __syncthreads();
#pragma unroll
    for (int i = 0; i < 16; i++)
      Wt[(long)(n0 + i * 4 + r4) * K + k0 + c] = tile[c][i * 4 + r4];
  } else {
    int lid = id - 3072;
    bool isq = lid < 4096;
    const float* x = isq ? src_q : src_kv;
    const float* g = isq ? gq : gkv;
    const float* b = isq ? bq : bkv;
    bf16* y = isq ? qn : kvn;
    long base = (long)(lid & 4095) * 1024;
    float v[4];
#pragma unroll
    for (int i = 0; i < 4; i++) v[i] = x[base + tid + i * 256];
    float s1 = v[0] + v[1] + v[2] + v[3];
    float s2 = v[0] * v[0] + v[1] * v[1] + v[2] * v[2] + v[3] * v[3];
#pragma unroll
    for (int off = 32; off; off >>= 1) {
      s1 += __shfl_xor(s1, off);
      s2 += __shfl_xor(s2, off);
    }
    int wave = tid >> 6, lane = tid & 63;
    if (lane == 0) { aux[0][wave] = s1; aux[1][wave] = s2; }
    __syncthreads();
    float S1 = aux[0][0] + aux[0][1] + aux[0][2] + aux[0][3];
    float S2 = aux[1][0] + aux[1][1] + aux[1][2] + aux[1][3];
    float mean = S1 * (1.0f / 1024.0f);
    float var = S2 * (1.0f / 1024.0f) - mean * mean;
    float rs = rsqrtf(var + 1e-5f);
#pragma unroll
    for (int i = 0; i < 4; i++) {
      int c = tid + i * 256;
      y[base + c] = (bf16)(((v[i] - mean) * rs) * g[c] + b[c]);
    }
  }
}

// ---------------- row LayerNorm: fp32 in -> bf16 out (mid-layer) ----------------
__global__ __launch_bounds__(256) void ln_f32(const float* __restrict__ x,
                                              const float* __restrict__ g,
                                              const float* __restrict__ b,
                                              bf16* __restrict__ y) {
  long base = (long)blockIdx.x * 1024;
  int tid = threadIdx.x;
  float v[4];
#pragma unroll
  for (int i = 0; i < 4; i++) v[i] = x[base + tid + i * 256];
  float s1 = v[0] + v[1] + v[2] + v[3];
  float s2 = v[0] * v[0] + v[1] * v[1] + v[2] * v[2] + v[3] * v[3];
#pragma unroll
  for (int off = 32; off; off >>= 1) {
    s1 += __shfl_xor(s1, off);
    s2 += __shfl_xor(s2, off);
  }
  __shared__ float aux[2][4];
  int wave = tid >> 6, lane = tid & 63;
  if (lane == 0) { aux[0][wave] = s1; aux[1][wave] = s2; }
  __syncthreads();
  float S1 = aux[0][0] + aux[0][1] + aux[0][2] + aux[0][3];
  float S2 = aux[1][0] + aux[1][1] + aux[1][2] + aux[1][3];
  float mean = S1 * (1.0f / 1024.0f);
  float var = S2 * (1.0f / 1024.0f) - mean * mean;
  float rs = rsqrtf(var + 1e-5f);
#pragma unroll
  for (int i = 0; i < 4; i++) {
    int c = tid + i * 256;
    y[base + c] = (bf16)(((v[i] - mean) * rs) * g[c] + b[c]);
  }
}

// ---------------- fused flash attention, swapped-QK^T in-register softmax ----------------
__global__ __launch_bounds__(256) void attn_fused(
    const bf16* __restrict__ Q,   // [4096][1024]
    const bf16* __restrict__ KV,  // [4096][2048], K at col h*64
    const bf16* __restrict__ Vt,  // [64 bh][64 d][1024 n]
    bf16* __restrict__ X) {       // [4096][1024]
  __shared__ __align__(16) bf16 Qs[128 * 64];
  __shared__ __align__(16) bf16 Ks[2][64 * 128];
  __shared__ __align__(16) bf16 Vs[2][64 * 128];
  int tid = threadIdx.x, wave = tid >> 6, lane = tid & 63;
  int l31 = lane & 31, h = lane >> 5;
  int bqx, bhy;
  xcd_swz(8, 64, bqx, bhy);
  int bh = bhy, b = bh >> 4, hd = bh & 15;
  const bf16* Qb = Q + (long)b * 1048576 + hd * 64;
  const bf16* Kb = KV + (long)b * 2097152 + hd * 64;
  const bf16* Vb = Vt + (long)bh * 65536;
  bf16* Xb = X + (long)b * 1048576 + hd * 64;
  int q0 = bqx * 128;

  const bf16* gk[4];
  const bf16* gv[4];
  int eoKV[4];
#pragma unroll
  for (int t = 0; t < 4; t++) {
    int eo = (t * 256 + tid) * 8;
    eoKV[t] = eo;
    int r2 = eo >> 7, pp = (eo & 127) >> 3, q = pp ^ (r2 & 15);
    gk[t] = &Kb[(long)(r2 + ((q >> 3) << 6)) * 2048 + ((q & 7) << 3)];
    gv[t] = &Vb[(long)r2 * 1024 + (q << 3)];
  }

#pragma unroll
  for (int t = 0; t < 4; t++) {
    int eo = (t * 256 + tid) * 8;
    int r = eo >> 6, p = (eo & 63) >> 3;
    int c = (p ^ (r & 7)) << 3;
    GLOAD_LDS16(&Qb[(long)(q0 + r) * 1024 + c], &Qs[eo]);
  }
#pragma unroll
  for (int t = 0; t < 4; t++) GLOAD_LDS16(gk[t], &Ks[0][eoKV[t]]);
#pragma unroll
  for (int t = 0; t < 4; t++) GLOAD_LDS16(gv[t], &Vs[0][eoKV[t]]);
  __syncthreads();

  bf16x8 qf[4];
  {
    int r = wave * 32 + l31;
#pragma unroll
    for (int dw = 0; dw < 4; dw++) {
      int p = (dw * 2 + h) ^ (r & 7);
      qf[dw] = *(const bf16x8*)&Qs[r * 64 + p * 8];
    }
  }

  const float C = 0.18033688011112042f;  // SCALE * log2(e)
  float m_run = -1e30f, l_run = 0.0f;
  f32x16 acc[2] = {};
  int cur = 0;

  for (int kc = 0; kc < 8; kc++) {
    if (kc < 7) {
#pragma unroll
      for (int t = 0; t < 4; t++)
        GLOAD_LDS16(gk[t] + (long)(kc + 1) * 128 * 2048, &Ks[cur ^ 1][eoKV[t]]);
#pragma unroll
      for (int t = 0; t < 4; t++)
        GLOAD_LDS16(gv[t] + (kc + 1) * 128, &Vs[cur ^ 1][eoKV[t]]);
    }
    const bf16* ks = Ks[cur];
    const bf16* vs = Vs[cur];

    f32x16 s[4] = {};
#pragma unroll
    for (int kt = 0; kt < 4; kt++) {
      int k = kt * 32 + l31;
      int r2 = k & 63, hi = k >> 6;
#pragma unroll
      for (int dw = 0; dw < 4; dw++) {
        int p = (hi * 8 + dw * 2 + h) ^ (r2 & 15);
        bf16x8 kf = *(const bf16x8*)&ks[r2 * 128 + p * 8];
        s[kt] = __builtin_amdgcn_mfma_f32_32x32x16_bf16(kf, qf[dw], s[kt], 0, 0, 0);
      }
    }

    float mk[4];
#pragma unroll
    for (int kt = 0; kt < 4; kt++) {
      float m01 = fmaxf(fmaxf(s[kt][0], s[kt][1]), fmaxf(s[kt][2], s[kt][3]));
      float m23 = fmaxf(fmaxf(s[kt][4], s[kt][5]), fmaxf(s[kt][6], s[kt][7]));
      float m45 = fmaxf(fmaxf(s[kt][8], s[kt][9]), fmaxf(s[kt][10], s[kt][11]));
      float m67 = fmaxf(fmaxf(s[kt][12], s[kt][13]), fmaxf(s[kt][14], s[kt][15]));
      mk[kt] = fmaxf(fmaxf(m01, m23), fmaxf(m45, m67));
    }
    float mx = fmaxf(fmaxf(mk[0], mk[1]), fmaxf(mk[2], mk[3]));
    mx = fmaxf(mx, __shfl_xor(mx, 32));
    float m_new = fmaxf(m_run, mx);
    float alpha = exp2f((m_run - m_new) * C);
    m_run = m_new;
    float mc = m_new * C;
    float rk[4];
#pragma unroll
    for (int kt = 0; kt < 4; kt++) {
      float r0 = 0.0f;
#pragma unroll
      for (int r = 0; r < 16; r++) {
        float pv = exp2f(s[kt][r] * C - mc);
        s[kt][r] = pv;
        r0 += pv;
      }
      rk[kt] = r0;
    }
    float rs = (rk[0] + rk[1]) + (rk[2] + rk[3]);
    rs += __shfl_xor(rs, 32);
    l_run = l_run * alpha + rs;
#pragma unroll
    for (int nt = 0; nt < 2; nt++)
#pragma unroll
      for (int r = 0; r < 16; r++) acc[nt][r] *= alpha;

#pragma unroll
    for (int kw = 0; kw < 8; kw++) {
      int kt = kw >> 1, rb = (kw & 1) * 8;
      u32 wA = pk_bf16(s[kt][rb + 0], s[kt][rb + 1]);
      u32 wB = pk_bf16(s[kt][rb + 2], s[kt][rb + 3]);
      u32 wC = pk_bf16(s[kt][rb + 4], s[kt][rb + 5]);
      u32 wD = pk_bf16(s[kt][rb + 6], s[kt][rb + 7]);
      plane32_swap(wA, wC);
      plane32_swap(wB, wD);
      u32x4 wv = {wA, wB, wC, wD};
      bf16x8 pf = __builtin_bit_cast(bf16x8, wv);
#pragma unroll
      for (int nt = 0; nt < 2; nt++) {
        int r2 = nt * 32 + l31;
        int p = (kw * 2 + h) ^ (r2 & 15);
        bf16x8 vf = *(const bf16x8*)&vs[r2 * 128 + p * 8];
        acc[nt] = __builtin_amdgcn_mfma_f32_32x32x16_bf16(vf, pf, acc[nt], 0, 0, 0);
      }
    }

    if (kc < 7) {
      __syncthreads();
      cur ^= 1;
    }
  }

  float fs = SCALE / l_run;
  bf16* Os = Qs;
  int qrow = wave * 32 + l31;
#pragma unroll
  for (int nt = 0; nt < 2; nt++)
#pragma unroll
    for (int g = 0; g < 4; g++) {
      u32 w0 = pk_bf16(acc[nt][g * 4 + 0] * fs, acc[nt][g * 4 + 1] * fs);
      u32 w1 = pk_bf16(acc[nt][g * 4 + 2] * fs, acc[nt][g * 4 + 3] * fs);
      int s8 = nt * 8 + g * 2 + h;
      int phys = s8 ^ (qrow & 15);
      u32x2 wv = {w0, w1};
      *(u32x2*)&Os[qrow * 64 + phys * 4] = wv;
    }
  int rrow = wave * 32 + (lane >> 1);
  int cbase = (lane & 1) * 32;
#pragma unroll
  for (int t2 = 0; t2 < 4; t2++) {
    int s0 = (lane & 1) * 8 + t2 * 2;
    u32x2 a = *(u32x2*)&Os[rrow * 64 + ((s0 ^ (rrow & 15)) * 4)];
    u32x2 bb = *(u32x2*)&Os[rrow * 64 + (((s0 + 1) ^ (rrow & 15)) * 4)];
    u32x4 o4 = {a[0], a[1], bb[0], bb[1]};
    *(u32x4*)&Xb[(long)(q0 + rrow) * 1024 + cbase + t2 * 8] = o4;
  }
}

// ---------------- pipelined gemm_p (R3-best pinned body), triple-buffered, 512 thr ----------------
template <int BM, int BN, int WR, int WC, int EPI, int CF32, int RBF16>
__global__ __launch_bounds__(512) void gemm_p(
    const bf16* __restrict__ A, int lda,
    const bf16* __restrict__ B, int ldb,
    void* __restrict__ Cv, int ldc, int K,
    const float* __restrict__ bias,
    const void* __restrict__ resv, int ldr) {
  constexpr int MT = BM / (16 * WR);
  constexpr int NT = BN / (16 * WC);
  constexpr int L = (BM + BN) / 64;
  constexpr int LA = BM / 64;
  constexpr int AE = BM * 64;
  constexpr int BUFE = (BM + BN) * 64;
  __shared__ __align__(16) bf16 lds[3 * BUFE];
  int tid = threadIdx.x;
  int wave = tid >> 6, lane = tid & 63;
  int wm = wave / WC, wn = wave % WC;
  int quad = lane >> 4, l16 = lane & 15;
  int bx, by;
  xcd_swz(gridDim.x, gridDim.y, bx, by);
  int m0 = by * BM, n0 = bx * BN;

  const bf16* gp[L];
  int lo[L];
#pragma unroll
  for (int i = 0; i < L; i++) {
    if (i < LA) {
      int eo = (i * 512 + tid) * 8;
      int r = eo >> 6, p = (eo & 63) >> 3;
      int c = (p ^ (r & 7)) << 3;
      gp[i] = &A[(long)(m0 + r) * lda + c];
      lo[i] = eo;
    } else {
      int eo = ((i - LA) * 512 + tid) * 8;
      int r = eo >> 6, p = (eo & 63) >> 3;
      int c = (p ^ (r & 7)) << 3;
      gp[i] = &B[(long)(n0 + r) * ldb + c];
      lo[i] = AE + eo;
    }
  }

  int ntk = K >> 6;
#pragma unroll
  for (int i = 0; i < L; i++) GLOAD_LDS16(gp[i], &lds[lo[i]]);
#pragma unroll
  for (int i = 0; i < L; i++) gp[i] += 64;
#pragma unroll
  for (int i = 0; i < L; i++) GLOAD_LDS16(gp[i], &lds[BUFE + lo[i]]);
#pragma unroll
  for (int i = 0; i < L; i++) gp[i] += 64;
  vmcnt_wait<L>();
  asm volatile("" ::: "memory");
  __builtin_amdgcn_s_barrier();

  f32x4 acc[MT][NT] = {};
  int b = 0;
  for (int t = 0; t < ntk; t++) {
    const bf16* Al = &lds[b * BUFE];
    const bf16* Bl = &lds[b * BUFE + AE];
    int b2 = b + 2; if (b2 >= 3) b2 -= 3;
    bool more = (t + 2) < ntk;

    bf16x8 af[2][MT], bv[2][NT];
#pragma unroll
    for (int ks = 0; ks < 2; ks++) {
#pragma unroll
      for (int mt = 0; mt < MT; mt++) {
        int row = wm * (BM / WR) + mt * 16 + l16;
        int p = (ks * 4 + quad) ^ (row & 7);
        af[ks][mt] = *(const bf16x8*)&Al[row * 64 + p * 8];
      }
#pragma unroll
      for (int nt = 0; nt < NT; nt++) {
        int row = wn * (BN / WC) + nt * 16 + l16;
        int p = (ks * 4 + quad) ^ (row & 7);
        bv[ks][nt] = *(const bf16x8*)&Bl[row * 64 + p * 8];
      }
    }
    if (more) {
#pragma unroll
      for (int i = 0; i < L; i++) GLOAD_LDS16(gp[i], &lds[b2 * BUFE + lo[i]]);
    }
    asm volatile("s_waitcnt lgkmcnt(0)" ::: "memory");
    __builtin_amdgcn_sched_barrier(0);
    __builtin_amdgcn_s_setprio(1);
#pragma unroll
    for (int ks = 0; ks < 2; ks++)
#pragma unroll
      for (int mt = 0; mt < MT; mt++)
#pragma unroll
        for (int nt = 0; nt < NT; nt++)
          acc[mt][nt] = __builtin_amdgcn_mfma_f32_16x16x32_bf16(
              af[ks][mt], bv[ks][nt], acc[mt][nt], 0, 0, 0);
    __builtin_amdgcn_s_setprio(0);
    __builtin_amdgcn_sched_barrier(0);
    if (more) {
      vmcnt_wait<L>();
    } else if (t + 1 < ntk) {
      vmcnt_wait<0>();
    }
    if (t + 1 < ntk) {
      asm volatile("" ::: "memory");
      __builtin_amdgcn_s_barrier();
    }
#pragma unroll
    for (int i = 0; i < L; i++) gp[i] += 64;
    b += 1; if (b == 3) b = 0;
  }

  int gm = m0 + wm * (BM / WR), gn = n0 + wn * (BN / WC);
#pragma unroll
  for (int nt = 0; nt < NT; nt++) {
    int col = gn + nt * 16 + l16;
    float bvb = (EPI != 0) ? bias[col] : 0.0f;
#pragma unroll
    for (int mt = 0; mt < MT; mt++) {
#pragma unroll
      for (int r = 0; r < 4; r++) {
        int row = gm + mt * 16 + quad * 4 + r;
        float v = acc[mt][nt][r] + bvb;
        if (EPI == 2) {
          v = 0.5f * v * (1.0f + erff(v * 0.70710678118654752f));
        } else if (EPI == 1) {
          float rv = RBF16 ? (float)((const bf16*)resv)[(long)row * ldr + col]
                           : ((const float*)resv)[(long)row * ldr + col];
          v += rv;
        }
        if (CF32)
          ((float*)Cv)[(long)row * ldc + col] = v;
        else
          ((bf16*)Cv)[(long)row * ldc + col] = (bf16)v;
      }
    }
  }
}

// ---------------- gemm_d: 128x128, 256 thr (4 waves), double-buffered, 2 blocks/CU ----------------
// EPI: 0 = bf16 store; 2 = gelu(acc+bias)->bf16; 3 = bf16 store + fused V^T write
// (cols>=1024 mirrored to Vt[bh][d][n], resv = Vt base; 4 consecutive n per thread
// -> aligned 8B bf16x4 store). Ledger as R8 (proven).
template <int EPI, int CF32, int RBF16>
__global__ __launch_bounds__(256, 2) void gemm_d(
    const bf16* __restrict__ A, int lda,
    const bf16* __restrict__ B, int ldb,
    void* __restrict__ Cv, int ldc, int K,
    const float* __restrict__ bias,
    const void* __restrict__ resv, int ldr) {
  constexpr int AE = 128 * 64;
  constexpr int BUFE = 256 * 64;
  __shared__ __align__(16) bf16 lds[2 * BUFE];  // 64 KB -> 2 blocks/CU
  int tid = threadIdx.x;
  int wave = tid >> 6, lane = tid & 63;
  int wm = wave >> 1, wn = wave & 1;
  int quad = lane >> 4, l16 = lane & 15;
  int bx, by;
  xcd_swz(gridDim.x, gridDim.y, bx, by);
  int m0 = by * 128, n0 = bx * 128;

  const bf16* gp[8];
  int lo[8];
#pragma unroll
  for (int i = 0; i < 8; i++) {
    if (i < 4) {
      int eo = (i * 256 + tid) * 8;
      int r = eo >> 6, p = (eo & 63) >> 3;
      int c = (p ^ (r & 7)) << 3;
      gp[i] = &A[(long)(m0 + r) * lda + c];
      lo[i] = eo;
    } else {
      int eo = ((i - 4) * 256 + tid) * 8;
      int r = eo >> 6, p = (eo & 63) >> 3;
      int c = (p ^ (r & 7)) << 3;
      gp[i] = &B[(long)(n0 + r) * ldb + c];
      lo[i] = AE + eo;
    }
  }

  int ntk = K >> 6;
#pragma unroll
  for (int i = 0; i < 8; i++) GLOAD_LDS16(gp[i], &lds[lo[i]]);
#pragma unroll
  for (int i = 0; i < 8; i++) gp[i] += 64;
  vmcnt_wait<0>();
  asm volatile("" ::: "memory");
  __builtin_amdgcn_s_barrier();

  f32x4 acc[4][4] = {};
  for (int t = 0; t < ntk; t++) {
    const bf16* Al = &lds[(t & 1) * BUFE];
    const bf16* Bl = &lds[(t & 1) * BUFE + AE];
    if (t + 1 < ntk) {
#pragma unroll
      for (int i = 0; i < 8; i++)
        GLOAD_LDS16(gp[i], &lds[((t + 1) & 1) * BUFE + lo[i]]);
#pragma unroll
      for (int i = 0; i < 8; i++) gp[i] += 64;
    }
    bf16x8 af[2][4], bv[2][4];
#pragma unroll
    for (int ks = 0; ks < 2; ks++) {
#pragma unroll
      for (int mt = 0; mt < 4; mt++) {
        int row = wm * 64 + mt * 16 + l16;
        int p = (ks * 4 + quad) ^ (row & 7);
        af[ks][mt] = *(const bf16x8*)&Al[row * 64 + p * 8];
      }
#pragma unroll
      for (int nt = 0; nt < 4; nt++) {
        int row = wn * 64 + nt * 16 + l16;
        int p = (ks * 4 + quad) ^ (row & 7);
        bv[ks][nt] = *(const bf16x8*)&Bl[row * 64 + p * 8];
      }
    }
    asm volatile("s_waitcnt lgkmcnt(0)" ::: "memory");
    __builtin_amdgcn_sched_barrier(0);
    __builtin_amdgcn_s_setprio(1);
#pragma unroll
    for (int ks = 0; ks < 2; ks++)
#pragma unroll
      for (int mt = 0; mt < 4; mt++)
#pragma unroll
        for (int nt = 0; nt < 4; nt++)
          acc[mt][nt] = __builtin_amdgcn_mfma_f32_16x16x32_bf16(
              af[ks][mt], bv[ks][nt], acc[mt][nt], 0, 0, 0);
    __builtin_amdgcn_s_setprio(0);
    __builtin_amdgcn_sched_barrier(0);
    if (t + 1 < ntk) {
      vmcnt_wait<0>();  // drain ok: co-resident block hides it (m114)
      asm volatile("" ::: "memory");
      __builtin_amdgcn_s_barrier();
    }
  }

  // epilogue
  int gm = m0 + wm * 64, gn = n0 + wn * 64;
#pragma unroll
  for (int nt = 0; nt < 4; nt++) {
    int col = gn + nt * 16 + l16;
    float bvb = (EPI == 1 || EPI == 2) ? bias[col] : 0.0f;
#pragma unroll
    for (int mt = 0; mt < 4; mt++) {
      bf16 vt4[4];
#pragma unroll
      for (int r = 0; r < 4; r++) {
        int row = gm + mt * 16 + quad * 4 + r;
        float v = acc[mt][nt][r] + bvb;
        if (EPI == 2) {
          v = 0.5f * v * (1.0f + erff(v * 0.70710678118654752f));
        } else if (EPI == 1) {
          float rv = RBF16 ? (float)((const bf16*)resv)[(long)row * ldr + col]
                           : ((const float*)resv)[(long)row * ldr + col];
          v += rv;
        }
        bf16 hv = (bf16)v;
        if (CF32)
          ((float*)Cv)[(long)row * ldc + col] = v;
        else
          ((bf16*)Cv)[(long)row * ldc + col] = hv;
        vt4[r] = hv;
      }
      if (EPI == 3 && col >= 1024) {
        int row0 = gm + mt * 16 + quad * 4;
        int bb = row0 >> 10, n = row0 & 1023;
        int hcol = col - 1024;
        bf16* Vt = (bf16*)resv;
        long vo = ((long)(bb * 16 + (hcol >> 6))) * 65536 + (long)(hcol & 63) * 1024 + n;
        bf16x4 pk4;
        pk4[0] = vt4[0]; pk4[1] = vt4[1]; pk4[2] = vt4[2]; pk4[3] = vt4[3];
        *(bf16x4*)&Vt[vo] = pk4;
      }
    }
  }
}

extern "C" void kernel_launch(void* const* d_in, const int* in_sizes, int n_in,
                              void* d_out, int out_size, void* d_ws, size_t ws_size,
                              hipStream_t stream) {
  const float* src_q  = (const float*)d_in[0];
  const float* src_kv = (const float*)d_in[1];
  const float* gq     = (const float*)d_in[2];
  const float* bq     = (const float*)d_in[3];
  const float* gkv    = (const float*)d_in[4];
  const float* bkv    = (const float*)d_in[5];
  const float* Wq     = (const float*)d_in[6];
  const float* Wkv    = (const float*)d_in[7];
  const float* Wproj  = (const float*)d_in[8];
  const float* bproj  = (const float*)d_in[9];
  const float* gn     = (const float*)d_in[10];
  const float* bn     = (const float*)d_in[11];
  const float* W1     = (const float*)d_in[12];
  const float* b1     = (const float*)d_in[13];
  const float* W2     = (const float*)d_in[14];
  const float* b2     = (const float*)d_in[15];
  float* out = (float*)d_out;

  char* ws = (char*)d_ws;
  const long MB = 1024 * 1024;
  bf16* Wq_t    = (bf16*)(ws + 0 * MB);
  bf16* Wkv_t   = (bf16*)(ws + 2 * MB);
  bf16* Wproj_t = (bf16*)(ws + 6 * MB);
  bf16* W1_t    = (bf16*)(ws + 8 * MB);
  bf16* W2_t    = (bf16*)(ws + 16 * MB);
  bf16* qn      = (bf16*)(ws + 24 * MB);
  bf16* kvn     = (bf16*)(ws + 32 * MB);
  bf16* Qm      = (bf16*)(ws + 40 * MB);
  bf16* KVm     = (bf16*)(ws + 48 * MB);
  bf16* Vt      = (bf16*)(ws + 64 * MB);
  bf16* xbuf    = (bf16*)(ws + 24 * MB);
  float* tbuf   = (float*)(ws + 48 * MB);
  bf16* sbuf    = (bf16*)(ws + 64 * MB);
  bf16* hbuf    = (bf16*)(ws + 72 * MB);

  // prologue: all 5 weight transposes + both input LayerNorms, one dispatch
  prologue<<<11264, 256, 0, stream>>>(
      Wq, Wkv, Wproj, W1, W2, Wq_t, Wkv_t, Wproj_t, W1_t, W2_t,
      src_q, src_kv, gq, bq, gkv, bkv, qn, kvn);

  // Q = qn @ Wq: 128x128 gemm_p, 256 blocks
  gemm_p<128, 128, 2, 4, 0, 0, 0><<<dim3(8, 32), 512, 0, stream>>>(
      qn, 1024, Wq_t, 1024, Qm, 1024, 1024, nullptr, nullptr, 0);
  // KV = kvn @ Wkv: gemm_d 128x128, 512 blocks -> 2/CU; fused V^T write (EPI=3)
  gemm_d<3, 0, 0><<<dim3(16, 32), 256, 0, stream>>>(
      kvn, 1024, Wkv_t, 1024, KVm, 2048, 1024, nullptr, Vt, 0);

  attn_fused<<<dim3(8, 64), 256, 0, stream>>>(Qm, KVm, Vt, xbuf);

  // tbuf = src_q + x @ Wproj + bproj
  gemm_p<128, 128, 2, 4, 1, 1, 0><<<dim3(8, 32), 512, 0, stream>>>(
      xbuf, 1024, Wproj_t, 1024, tbuf, 1024, 1024, bproj, src_q, 1024);
  ln_f32<<<4096, 256, 0, stream>>>(tbuf, gn, bn, sbuf);
  // hbuf = gelu(sbuf @ W1 + b1): gemm_d 128x128, 1024 blocks -> 2/CU
  gemm_d<2, 0, 0><<<dim3(32, 32), 256, 0, stream>>>(
      sbuf, 1024, W1_t, 1024, hbuf, 4096, 1024, b1, nullptr, 0);
  // out = sbuf + hbuf @ W2 + b2: gemm_p, 256 blocks
  gemm_p<128, 128, 2, 4, 1, 1, 1><<<dim3(8, 32), 512, 0, stream>>>(
      hbuf, 4096, W2_t, 4096, out, 1024, 4096, b2, sbuf, 1024);
}